// Round 1
// baseline (2681.248 us; speedup 1.0000x reference)
//
#include <hip/hip_runtime.h>
#include <cmath>

#define N_SP 4096   // H*W
#define C_CH 512
#define B_SZ 4

__device__ __forceinline__ float wave_reduce_sum(float v) {
    #pragma unroll
    for (int off = 32; off; off >>= 1) v += __shfl_xor(v, off, 64);
    return v;
}
__device__ __forceinline__ float wave_reduce_max(float v) {
    #pragma unroll
    for (int off = 32; off; off >>= 1) v = fmaxf(v, __shfl_xor(v, off, 64));
    return v;
}

// ---------------- channel norm: one block per (b,c) row of 4096 ----------------
__global__ __launch_bounds__(256) void channel_norm_kernel(const float* __restrict__ x,
                                                           float* __restrict__ y) {
    const size_t base = (size_t)blockIdx.x * N_SP;
    const int t = threadIdx.x;
    float v[16];
    float s = 0.f, ss = 0.f;
    #pragma unroll
    for (int i = 0; i < 16; ++i) {
        float a = x[base + t + 256 * i];
        v[i] = a; s += a; ss += a * a;
    }
    s = wave_reduce_sum(s);
    ss = wave_reduce_sum(ss);
    __shared__ float rs[4], rss[4];
    const int wave = t >> 6;
    if ((t & 63) == 0) { rs[wave] = s; rss[wave] = ss; }
    __syncthreads();
    const float S  = rs[0] + rs[1] + rs[2] + rs[3];
    const float SS = rss[0] + rss[1] + rss[2] + rss[3];
    const float mean = S * (1.f / N_SP);
    const float var  = (SS - S * mean) * (1.f / (N_SP - 1));   // ddof=1 (unbiased)
    const float inv  = rsqrtf(var + 1e-5f);
    #pragma unroll
    for (int i = 0; i < 16; ++i) y[base + t + 256 * i] = (v[i] - mean) * inv;
}

// ---------------- conv1x1 GEMM: Y[b,m,n] = sum_k W[m,k] X[b,k,n] + bias[m] (+res) ----------------
// 64x64 tile, K-chunk 16, 256 threads, 4x4 micro-tile.
__global__ __launch_bounds__(256) void gemm_conv(const float* __restrict__ A,   // W [M,K]
                                                 const float* __restrict__ X,   // [B,K,N]
                                                 const float* __restrict__ bias,
                                                 const float* __restrict__ res, // [B,M,N] or null
                                                 float* __restrict__ Y,         // [B,M,N]
                                                 int M, int K, int N) {
    __shared__ float As[16][64];   // As[k][m]
    __shared__ float Bs[16][64];   // Bs[k][n]
    const int tx = threadIdx.x & 15, ty = threadIdx.x >> 4;
    const int n0 = blockIdx.x * 64, m0 = blockIdx.y * 64;
    const float* Xb = X + (size_t)blockIdx.z * K * N;
    float acc[4][4] = {};
    const int e = threadIdx.x << 2;
    for (int k0 = 0; k0 < K; k0 += 16) {
        {   // A tile (transpose into LDS): W[m0+m][k0+k..k+3]
            const int m = e >> 4, k = e & 12;
            const float4 a4 = *(const float4*)(A + (size_t)(m0 + m) * K + k0 + k);
            As[k + 0][m] = a4.x; As[k + 1][m] = a4.y; As[k + 2][m] = a4.z; As[k + 3][m] = a4.w;
        }
        {   // B tile: X[k0+k][n0+n..n+3]
            const int k = e >> 6, n = e & 63;
            *(float4*)&Bs[k][n] = *(const float4*)(Xb + (size_t)(k0 + k) * N + n0 + n);
        }
        __syncthreads();
        #pragma unroll
        for (int k = 0; k < 16; ++k) {
            const float4 a = *(const float4*)&As[k][ty << 2];
            const float4 b = *(const float4*)&Bs[k][tx << 2];
            const float av_[4] = {a.x, a.y, a.z, a.w};
            const float bv_[4] = {b.x, b.y, b.z, b.w};
            #pragma unroll
            for (int i = 0; i < 4; ++i)
                #pragma unroll
                for (int j = 0; j < 4; ++j)
                    acc[i][j] += av_[i] * bv_[j];
        }
        __syncthreads();
    }
    const size_t outBase = (size_t)blockIdx.z * M * N;
    #pragma unroll
    for (int i = 0; i < 4; ++i) {
        const int m = m0 + (ty << 2) + i;
        const float bv = bias[m];
        float4 r;
        r.x = acc[i][0] + bv; r.y = acc[i][1] + bv; r.z = acc[i][2] + bv; r.w = acc[i][3] + bv;
        const size_t off = outBase + (size_t)m * N + n0 + (tx << 2);
        if (res) {
            const float4 rv = *(const float4*)(res + off);
            r.x += rv.x; r.y += rv.y; r.z += rv.z; r.w += rv.w;
        }
        *(float4*)(Y + off) = r;
    }
}

// ---------------- scores: S[i,j] = sum_k F[k,i] G[k,j]  (TN GEMM) ----------------
__global__ __launch_bounds__(256) void gemm_tn(const float* __restrict__ F,  // [K,N]
                                               const float* __restrict__ G,  // [K,N]
                                               float* __restrict__ S,        // [N,N]
                                               int K, int N) {
    __shared__ float As[16][64];   // As[k][i]
    __shared__ float Bs[16][64];   // Bs[k][j]
    const int tx = threadIdx.x & 15, ty = threadIdx.x >> 4;
    const int j0 = blockIdx.x * 64, i0 = blockIdx.y * 64;
    float acc[4][4] = {};
    const int e = threadIdx.x << 2;
    const int k = e >> 6, p = e & 63;
    for (int k0 = 0; k0 < K; k0 += 16) {
        *(float4*)&As[k][p] = *(const float4*)(F + (size_t)(k0 + k) * N + i0 + p);
        *(float4*)&Bs[k][p] = *(const float4*)(G + (size_t)(k0 + k) * N + j0 + p);
        __syncthreads();
        #pragma unroll
        for (int kk = 0; kk < 16; ++kk) {
            const float4 a = *(const float4*)&As[kk][ty << 2];
            const float4 b = *(const float4*)&Bs[kk][tx << 2];
            const float av_[4] = {a.x, a.y, a.z, a.w};
            const float bv_[4] = {b.x, b.y, b.z, b.w};
            #pragma unroll
            for (int i = 0; i < 4; ++i)
                #pragma unroll
                for (int j = 0; j < 4; ++j)
                    acc[i][j] += av_[i] * bv_[j];
        }
        __syncthreads();
    }
    #pragma unroll
    for (int i = 0; i < 4; ++i) {
        float4 r; r.x = acc[i][0]; r.y = acc[i][1]; r.z = acc[i][2]; r.w = acc[i][3];
        *(float4*)(S + (size_t)(i0 + (ty << 2) + i) * N + j0 + (tx << 2)) = r;
    }
}

// ---------------- softmax over j, one block per row ----------------
__global__ __launch_bounds__(256) void softmax_kernel(float* __restrict__ S) {
    float* row = S + (size_t)blockIdx.x * N_SP;
    const int t = threadIdx.x;
    float v[16];
    float mx = -1e30f;
    #pragma unroll
    for (int i = 0; i < 16; ++i) { v[i] = row[t + 256 * i]; mx = fmaxf(mx, v[i]); }
    mx = wave_reduce_max(mx);
    __shared__ float red[4];
    const int wave = t >> 6;
    if ((t & 63) == 0) red[wave] = mx;
    __syncthreads();
    mx = fmaxf(fmaxf(red[0], red[1]), fmaxf(red[2], red[3]));
    float sum = 0.f;
    #pragma unroll
    for (int i = 0; i < 16; ++i) { v[i] = expf(v[i] - mx); sum += v[i]; }
    sum = wave_reduce_sum(sum);
    __syncthreads();
    if ((t & 63) == 0) red[wave] = sum;
    __syncthreads();
    const float inv = 1.f / (red[0] + red[1] + red[2] + red[3]);
    #pragma unroll
    for (int i = 0; i < 16; ++i) row[t + 256 * i] = v[i] * inv;
}

// ---------------- PV: O[c,i] = sum_j H[c,j] P[i,j]  (NT GEMM) ----------------
__global__ __launch_bounds__(256) void gemm_nt(const float* __restrict__ H,  // [C,N]
                                               const float* __restrict__ P,  // [N,N] row-major (i major)
                                               float* __restrict__ O,        // [C,N]
                                               int C, int N) {
    __shared__ float As[16][64];   // As[j][c]
    __shared__ float Bs[16][64];   // Bs[j][i]
    const int tx = threadIdx.x & 15, ty = threadIdx.x >> 4;
    const int i0 = blockIdx.x * 64, c0 = blockIdx.y * 64;
    float acc[4][4] = {};
    const int e = threadIdx.x << 2;
    const int r = e >> 4, kb = e & 12;
    for (int k0 = 0; k0 < N; k0 += 16) {
        {
            const float4 a4 = *(const float4*)(H + (size_t)(c0 + r) * N + k0 + kb);
            As[kb + 0][r] = a4.x; As[kb + 1][r] = a4.y; As[kb + 2][r] = a4.z; As[kb + 3][r] = a4.w;
        }
        {
            const float4 b4 = *(const float4*)(P + (size_t)(i0 + r) * N + k0 + kb);
            Bs[kb + 0][r] = b4.x; Bs[kb + 1][r] = b4.y; Bs[kb + 2][r] = b4.z; Bs[kb + 3][r] = b4.w;
        }
        __syncthreads();
        #pragma unroll
        for (int kk = 0; kk < 16; ++kk) {
            const float4 a = *(const float4*)&As[kk][ty << 2];
            const float4 b = *(const float4*)&Bs[kk][tx << 2];
            const float av_[4] = {a.x, a.y, a.z, a.w};
            const float bv_[4] = {b.x, b.y, b.z, b.w};
            #pragma unroll
            for (int i = 0; i < 4; ++i)
                #pragma unroll
                for (int j = 0; j < 4; ++j)
                    acc[i][j] += av_[i] * bv_[j];
        }
        __syncthreads();
    }
    #pragma unroll
    for (int i = 0; i < 4; ++i) {
        float4 r4; r4.x = acc[i][0]; r4.y = acc[i][1]; r4.z = acc[i][2]; r4.w = acc[i][3];
        *(float4*)(O + (size_t)(c0 + (ty << 2) + i) * N + i0 + (tx << 2)) = r4;
    }
}

extern "C" void kernel_launch(void* const* d_in, const int* in_sizes, int n_in,
                              void* d_out, int out_size, void* d_ws, size_t ws_size,
                              hipStream_t stream) {
    const float* f_c   = (const float*)d_in[0];
    const float* f_s   = (const float*)d_in[1];
    const float* W_c1  = (const float*)d_in[2];
    const float* b_c1  = (const float*)d_in[3];
    const float* W_s1  = (const float*)d_in[4];
    const float* b_s1  = (const float*)d_in[5];
    const float* W_s2  = (const float*)d_in[6];
    const float* b_s2  = (const float*)d_in[7];
    const float* W_csc = (const float*)d_in[8];
    const float* b_csc = (const float*)d_in[9];
    float* out = (float*)d_out;

    // workspace layout (floats). total = 6 * 8M floats = 192 MB.
    const size_t plane = (size_t)B_SZ * C_CH * N_SP;   // 8,388,608 floats
    float* ws    = (float*)d_ws;
    float* hat_c = ws;
    float* hat_s = ws + plane;
    float* fq    = ws + 2 * plane;
    float* gk    = ws + 3 * plane;
    float* hv    = ws + 4 * plane;
    float* av    = ws + 5 * plane;
    // scores [N,N] = 16M floats = exactly hat_c+hat_s region, which is dead after the convs.
    float* scores = ws;

    channel_norm_kernel<<<B_SZ * C_CH, 256, 0, stream>>>(f_c, hat_c);
    channel_norm_kernel<<<B_SZ * C_CH, 256, 0, stream>>>(f_s, hat_s);

    dim3 gconv(N_SP / 64, C_CH / 64, B_SZ);
    gemm_conv<<<gconv, 256, 0, stream>>>(W_c1, hat_c, b_c1, nullptr, fq, C_CH, C_CH, N_SP);
    gemm_conv<<<gconv, 256, 0, stream>>>(W_s1, hat_s, b_s1, nullptr, gk, C_CH, C_CH, N_SP);
    gemm_conv<<<gconv, 256, 0, stream>>>(W_s2, hat_s, b_s2, nullptr, hv, C_CH, C_CH, N_SP);

    const size_t bstride = (size_t)C_CH * N_SP;
    for (int b = 0; b < B_SZ; ++b) {
        gemm_tn<<<dim3(N_SP / 64, N_SP / 64), 256, 0, stream>>>(
            fq + b * bstride, gk + b * bstride, scores, C_CH, N_SP);
        softmax_kernel<<<N_SP, 256, 0, stream>>>(scores);
        gemm_nt<<<dim3(N_SP / 64, C_CH / 64), 256, 0, stream>>>(
            hv + b * bstride, scores, av + b * bstride, C_CH, N_SP);
    }
    gemm_conv<<<gconv, 256, 0, stream>>>(W_csc, av, b_csc, f_c, out, C_CH, C_CH, N_SP);
}

// Round 2
// 883.049 us; speedup vs baseline: 3.0364x; 3.0364x over previous
//
#include <hip/hip_runtime.h>
#include <cmath>

typedef unsigned short u16;
typedef __attribute__((ext_vector_type(8))) short bf16x8;
typedef __attribute__((ext_vector_type(4))) float f32x4;

#define N_SP 4096
#define C_CH 512
#define B_SZ 4

__device__ __forceinline__ u16 f2bf(float f) {
    union { float f; unsigned u; } x; x.f = f;
    unsigned r = x.u + 0x7fffu + ((x.u >> 16) & 1u);
    return (u16)(r >> 16);
}
__device__ __forceinline__ float bf2f(u16 h) {
    union { unsigned u; float f; } x; x.u = ((unsigned)h) << 16;
    return x.f;
}
__device__ __forceinline__ void async_cp16(const void* g, void* l) {
    __builtin_amdgcn_global_load_lds((const __attribute__((address_space(1))) unsigned*)g,
                                     (__attribute__((address_space(3))) unsigned*)l, 16, 0, 0);
}

__device__ __forceinline__ float wave_reduce_sum(float v) {
    #pragma unroll
    for (int off = 32; off; off >>= 1) v += __shfl_xor(v, off, 64);
    return v;
}
__device__ __forceinline__ float wave_reduce_max(float v) {
    #pragma unroll
    for (int off = 32; off; off >>= 1) v = fmaxf(v, __shfl_xor(v, off, 64));
    return v;
}

// ---------------- per-(b,c) stats: mean + rsqrt(var_unbiased + eps) ----------------
__global__ __launch_bounds__(256) void stats_kernel(const float* __restrict__ fc,
                                                    const float* __restrict__ fs,
                                                    float* __restrict__ stats) {
    const int idx = blockIdx.x;                    // 0..4095 (2048 fc + 2048 fs)
    const float* src = (idx < 2048 ? fc : fs) + (size_t)(idx & 2047) * N_SP;
    const int t = threadIdx.x;
    float s = 0.f, ss = 0.f;
    #pragma unroll
    for (int i = 0; i < 4; ++i) {
        float4 v = *(const float4*)(src + i * 1024 + t * 4);
        s  += v.x + v.y + v.z + v.w;
        ss += v.x * v.x + v.y * v.y + v.z * v.z + v.w * v.w;
    }
    s = wave_reduce_sum(s); ss = wave_reduce_sum(ss);
    __shared__ float rs[4], rss[4];
    const int wave = t >> 6;
    if ((t & 63) == 0) { rs[wave] = s; rss[wave] = ss; }
    __syncthreads();
    if (t == 0) {
        const float S  = rs[0] + rs[1] + rs[2] + rs[3];
        const float SS = rss[0] + rss[1] + rss[2] + rss[3];
        const float mean = S * (1.f / N_SP);
        const float var  = (SS - S * mean) * (1.f / (N_SP - 1));
        stats[idx * 2 + 0] = mean;
        stats[idx * 2 + 1] = rsqrtf(var + 1e-5f);
    }
}

// ---------------- normalize + transpose + hi/lo bf16 split ----------------
// in:  x [b][c][n] fp32     out: x̂ᵀ [b][n][c] bf16 hi/lo
__global__ __launch_bounds__(256) void norm_transpose(
        const float* __restrict__ fc, const float* __restrict__ fs,
        const float* __restrict__ stats,
        u16* __restrict__ xc_h, u16* __restrict__ xc_l,
        u16* __restrict__ xs_h, u16* __restrict__ xs_l) {
    __shared__ float tile[64][65];
    __shared__ float mi[64][2];
    const int t = threadIdx.x;
    const int n0 = blockIdx.x * 64, c0 = blockIdx.y * 64;
    const int z = blockIdx.z;                      // 0..7: (which<<2)|b
    const int b = z & 3, which = z >> 2;
    const float* src = which ? fs : fc;
    u16* dh = which ? xs_h : xc_h;
    u16* dl = which ? xs_l : xc_l;
    const float* st = stats + ((size_t)which * 2048 + b * 512 + c0) * 2;
    if (t < 128) ((float*)mi)[t] = st[t];
    __syncthreads();
    const int r = t >> 4, q4 = (t & 15) * 4;
    #pragma unroll
    for (int it = 0; it < 4; ++it) {
        const int row = it * 16 + r;
        float4 v = *(const float4*)(src + ((size_t)b * C_CH + c0 + row) * N_SP + n0 + q4);
        const float mean = mi[row][0], inv = mi[row][1];
        tile[row][q4 + 0] = (v.x - mean) * inv;
        tile[row][q4 + 1] = (v.y - mean) * inv;
        tile[row][q4 + 2] = (v.z - mean) * inv;
        tile[row][q4 + 3] = (v.w - mean) * inv;
    }
    __syncthreads();
    #pragma unroll
    for (int it = 0; it < 4; ++it) {
        const int nrow = it * 16 + r;
        float a[4];
        #pragma unroll
        for (int i = 0; i < 4; ++i) a[i] = tile[q4 + i][nrow];
        ushort4 h4, l4;
        u16 h;
        h = f2bf(a[0]); h4.x = h; l4.x = f2bf(a[0] - bf2f(h));
        h = f2bf(a[1]); h4.y = h; l4.y = f2bf(a[1] - bf2f(h));
        h = f2bf(a[2]); h4.z = h; l4.z = f2bf(a[2] - bf2f(h));
        h = f2bf(a[3]); h4.w = h; l4.w = f2bf(a[3] - bf2f(h));
        const size_t dst = ((size_t)b * N_SP + n0 + nrow) * C_CH + c0 + q4;
        *(ushort4*)(dh + dst) = h4;
        *(ushort4*)(dl + dst) = l4;
    }
}

// ---------------- weight split to bf16 hi (+lo) ----------------
__global__ __launch_bounds__(256) void wsplit(const float* __restrict__ W,
                                              u16* __restrict__ h, u16* __restrict__ l) {
    const int i = blockIdx.x * 256 + threadIdx.x;
    const float v = W[i];
    const u16 hh = f2bf(v);
    h[i] = hh;
    if (l) l[i] = f2bf(v - bf2f(hh));
}

// ---------------- MFMA GEMM (bt form): D[m][n] = sum_k A[m][k] * B[n][k] ----------------
// SPLIT: A,B given as (hi,lo) bf16 planes; 3-term product for ~fp32 accuracy.
enum { OUT_F32 = 0, OUT_BF16 = 1, OUT_BF16X2 = 2 };

template<int SPLIT, int OUTMODE, int TN>
__global__ __launch_bounds__(256) void gemm_bt(
    const u16* __restrict__ Ah, const u16* __restrict__ Al,
    const u16* __restrict__ Bh, const u16* __restrict__ Bl,
    float* __restrict__ Df, u16* __restrict__ Dh, u16* __restrict__ Dl,
    const float* __restrict__ bias_m, const float* __restrict__ bias_n,
    const float* __restrict__ res,
    int M, int N, int K, int lda, int ldb, int ldd,
    size_t sA, size_t sB, size_t sD, size_t sR)
{
    constexpr int TM = 128, BK = 32;
    constexpr int NP = SPLIT ? 2 : 1;
    constexpr int FM = (TN == 128) ? 4 : 2;
    __shared__ u16 smem[NP * (TM + TN) * BK];
    u16* As[2] = { smem, smem + TM * BK };
    u16* Bs[2] = { smem + NP * TM * BK, smem + NP * TM * BK + TN * BK };

    const int t = threadIdx.x;
    const int l = t & 63, w = t >> 6;
    const int m0 = blockIdx.y * TM, n0 = blockIdx.x * TN;
    const size_t zb = blockIdx.z;
    const u16* pAh = Ah + zb * sA + (size_t)m0 * lda;
    const u16* pAl = SPLIT ? (Al + zb * sA + (size_t)m0 * lda) : nullptr;
    const u16* pBh = Bh + zb * sB + (size_t)n0 * ldb;
    const u16* pBl = SPLIT ? (Bl + zb * sB + (size_t)n0 * ldb) : nullptr;

    int wr, wc;
    if (TN == 128) { wr = (w & 1) * 64; wc = (w >> 1) * 64; }
    else           { wr = w * 32;       wc = 0; }

    f32x4 acc[FM][4] = {};

    for (int k0 = 0; k0 < K; k0 += BK) {
        #pragma unroll
        for (int it = 0; it < TM / 64; ++it) {
            const int L = it * 256 + t;
            const int row = L >> 2, cb = (L & 3) * 8;
            async_cp16(pAh + (size_t)row * lda + k0 + cb, As[0] + L * 8);
            if (SPLIT) async_cp16(pAl + (size_t)row * lda + k0 + cb, As[1] + L * 8);
        }
        #pragma unroll
        for (int it = 0; it < TN / 64; ++it) {
            const int L = it * 256 + t;
            const int row = L >> 2, cb = (L & 3) * 8;
            async_cp16(pBh + (size_t)row * ldb + k0 + cb, Bs[0] + L * 8);
            if (SPLIT) async_cp16(pBl + (size_t)row * ldb + k0 + cb, Bs[1] + L * 8);
        }
        __syncthreads();
        bf16x8 af[NP][FM], bfr[NP][4];
        #pragma unroll
        for (int p = 0; p < NP; ++p) {
            #pragma unroll
            for (int i = 0; i < FM; ++i)
                af[p][i] = *(const bf16x8*)(As[p] + (wr + i * 16 + (l & 15)) * BK + (l >> 4) * 8);
            #pragma unroll
            for (int j = 0; j < 4; ++j)
                bfr[p][j] = *(const bf16x8*)(Bs[p] + (wc + j * 16 + (l & 15)) * BK + (l >> 4) * 8);
        }
        #pragma unroll
        for (int i = 0; i < FM; ++i)
            #pragma unroll
            for (int j = 0; j < 4; ++j) {
                acc[i][j] = __builtin_amdgcn_mfma_f32_16x16x32_bf16(af[0][i], bfr[0][j], acc[i][j], 0, 0, 0);
                if (SPLIT) {
                    acc[i][j] = __builtin_amdgcn_mfma_f32_16x16x32_bf16(af[0][i], bfr[1][j], acc[i][j], 0, 0, 0);
                    acc[i][j] = __builtin_amdgcn_mfma_f32_16x16x32_bf16(af[1][i], bfr[0][j], acc[i][j], 0, 0, 0);
                }
            }
        __syncthreads();
    }

    const int em = m0 + wr + (l >> 4) * 4;
    const int en = n0 + wc + (l & 15);
    #pragma unroll
    for (int i = 0; i < FM; ++i) {
        #pragma unroll
        for (int j = 0; j < 4; ++j) {
            const int nn = en + j * 16;
            const float bn = bias_n ? bias_n[nn] : 0.f;
            #pragma unroll
            for (int r = 0; r < 4; ++r) {
                const int mm = em + i * 16 + r;
                float v = acc[i][j][r] + bn;
                if (bias_m) v += bias_m[mm];
                const size_t off = zb * sD + (size_t)mm * ldd + nn;
                if (OUTMODE == OUT_F32) {
                    if (res) v += res[zb * sR + (size_t)mm * ldd + nn];
                    Df[off] = v;
                } else if (OUTMODE == OUT_BF16) {
                    Dh[off] = f2bf(v);
                } else {
                    const u16 h = f2bf(v);
                    Dh[off] = h;
                    Dl[off] = f2bf(v - bf2f(h));
                }
            }
        }
    }
}

// ---------------- softmax row-wise; writes P bf16 in-place (row stride 8192 u16) ----------------
__global__ __launch_bounds__(256) void softmax_kernel(float* __restrict__ S) {
    float* row = S + (size_t)blockIdx.x * N_SP;
    u16* prow = (u16*)S + (size_t)blockIdx.x * (N_SP * 2);
    const int t = threadIdx.x;
    float v[16];
    float mx = -1e30f;
    #pragma unroll
    for (int i = 0; i < 16; ++i) { v[i] = row[t + 256 * i]; mx = fmaxf(mx, v[i]); }
    mx = wave_reduce_max(mx);
    __shared__ float red[4];
    const int wave = t >> 6;
    if ((t & 63) == 0) red[wave] = mx;
    __syncthreads();           // also orders all loads before the in-place stores below
    mx = fmaxf(fmaxf(red[0], red[1]), fmaxf(red[2], red[3]));
    float sum = 0.f;
    #pragma unroll
    for (int i = 0; i < 16; ++i) { v[i] = expf(v[i] - mx); sum += v[i]; }
    sum = wave_reduce_sum(sum);
    __syncthreads();
    if ((t & 63) == 0) red[wave] = sum;
    __syncthreads();
    const float inv = 1.f / (red[0] + red[1] + red[2] + red[3]);
    #pragma unroll
    for (int i = 0; i < 16; ++i) prow[t + 256 * i] = f2bf(v[i] * inv);
}

extern "C" void kernel_launch(void* const* d_in, const int* in_sizes, int n_in,
                              void* d_out, int out_size, void* d_ws, size_t ws_size,
                              hipStream_t stream) {
    const float* f_c   = (const float*)d_in[0];
    const float* f_s   = (const float*)d_in[1];
    const float* W_c1  = (const float*)d_in[2];
    const float* b_c1  = (const float*)d_in[3];
    const float* W_s1  = (const float*)d_in[4];
    const float* b_s1  = (const float*)d_in[5];
    const float* W_s2  = (const float*)d_in[6];
    const float* b_s2  = (const float*)d_in[7];
    const float* W_s2b = b_s2 ? nullptr : nullptr; (void)W_s2b;
    const float* W_csc = (const float*)d_in[8];
    const float* b_csc = (const float*)d_in[9];

    const size_t PB = (size_t)N_SP * C_CH;           // per-batch plane elements (2M)
    const size_t PL = (size_t)B_SZ * PB;             // full plane elements (8M)

    u16* xc_h = (u16*)d_ws;
    u16* xc_l = xc_h + PL;
    u16* xs_h = xc_l + PL;
    u16* xs_l = xs_h + PL;
    float* Sbuf = (float*)d_ws;                      // aliases x̂ planes (dead by then)
    u16* f_h = xs_l + PL;
    u16* f_l = f_h + PL;
    u16* g_h = f_l + PL;
    u16* g_l = g_h + PL;
    u16* h_b = g_l + PL;
    u16* O_b = h_b + PL;
    u16* Wc1h = O_b + PL;
    u16* Wc1l = Wc1h + 262144;
    u16* Ws1h = Wc1l + 262144;
    u16* Ws1l = Ws1h + 262144;
    u16* Ws2h = Ws1l + 262144;
    u16* Wcsch = Ws2h + 262144;
    float* stats = (float*)(Wcsch + 262144);

    stats_kernel<<<4096, 256, 0, stream>>>(f_c, f_s, stats);
    norm_transpose<<<dim3(64, 8, 8), 256, 0, stream>>>(f_c, f_s, stats, xc_h, xc_l, xs_h, xs_l);
    wsplit<<<1024, 256, 0, stream>>>(W_c1, Wc1h, Wc1l);
    wsplit<<<1024, 256, 0, stream>>>(W_s1, Ws1h, Ws1l);
    wsplit<<<1024, 256, 0, stream>>>(W_s2, Ws2h, nullptr);
    wsplit<<<1024, 256, 0, stream>>>(W_csc, Wcsch, nullptr);

    // fᵀ[i][o] = Σ_c x̂cᵀ[i][c] W_c1[o][c] + b_c1[o]   (split3, bf16 hi/lo out)
    gemm_bt<1, OUT_BF16X2, 128><<<dim3(4, 32, B_SZ), 256, 0, stream>>>(
        xc_h, xc_l, Wc1h, Wc1l, nullptr, f_h, f_l,
        nullptr, b_c1, nullptr,
        N_SP, C_CH, C_CH, C_CH, C_CH, C_CH, PB, 0, PB, 0);
    // gᵀ
    gemm_bt<1, OUT_BF16X2, 128><<<dim3(4, 32, B_SZ), 256, 0, stream>>>(
        xs_h, xs_l, Ws1h, Ws1l, nullptr, g_h, g_l,
        nullptr, b_s1, nullptr,
        N_SP, C_CH, C_CH, C_CH, C_CH, C_CH, PB, 0, PB, 0);
    // h[c][j] = Σ_k W_s2[c][k] x̂sᵀ[j][k] + b_s2[c]   (plain bf16)
    gemm_bt<0, OUT_BF16, 128><<<dim3(32, 4, B_SZ), 256, 0, stream>>>(
        Ws2h, nullptr, xs_h, nullptr, nullptr, h_b, nullptr,
        b_s2, nullptr, nullptr,
        C_CH, N_SP, C_CH, C_CH, C_CH, N_SP, 0, PB, PB, 0);

    for (int b = 0; b < B_SZ; ++b) {
        // S[i][j] = Σ_c fᵀ[i][c] gᵀ[j][c]   (split3, fp32 out)
        gemm_bt<1, OUT_F32, 128><<<dim3(32, 32, 1), 256, 0, stream>>>(
            f_h + b * PB, f_l + b * PB, g_h + b * PB, g_l + b * PB, Sbuf, nullptr, nullptr,
            nullptr, nullptr, nullptr,
            N_SP, N_SP, C_CH, C_CH, C_CH, N_SP, 0, 0, 0, 0);
        softmax_kernel<<<N_SP, 256, 0, stream>>>(Sbuf);
        // Oᵀ[i][c] = Σ_j P[i][j] h[c][j]   (plain bf16; P row stride 8192)
        gemm_bt<0, OUT_BF16, 64><<<dim3(8, 32, 1), 256, 0, stream>>>(
            (u16*)Sbuf, nullptr, h_b + b * PB, nullptr, nullptr, O_b + b * PB, nullptr,
            nullptr, nullptr, nullptr,
            N_SP, C_CH, N_SP, 2 * N_SP, N_SP, C_CH, 0, 0, 0, 0);
    }
    // out[o][i] = Σ_c W_csc[o][c] Oᵀ[i][c] + b_csc[o] + f_c   (fp32 out)
    gemm_bt<0, OUT_F32, 128><<<dim3(32, 4, B_SZ), 256, 0, stream>>>(
        Wcsch, nullptr, O_b, nullptr, (float*)d_out, nullptr, nullptr,
        b_csc, nullptr, f_c,
        C_CH, N_SP, C_CH, C_CH, C_CH, N_SP, 0, PB, PB, PB);
}

// Round 3
// 521.361 us; speedup vs baseline: 5.1428x; 1.6937x over previous
//
#include <hip/hip_runtime.h>

typedef unsigned short u16;
typedef __attribute__((ext_vector_type(8))) _Float16 f16x8;
typedef __attribute__((ext_vector_type(4))) float f32x4;

#define N_SP 4096
#define C_CH 512
#define B_SZ 4

struct PtrTab { u16* p[4]; };

__device__ __forceinline__ u16 f2h(float f) {
    _Float16 h = (_Float16)f;
    union { _Float16 h; u16 u; } x; x.h = h; return x.u;
}
__device__ __forceinline__ float h2f(u16 u) {
    union { u16 u; _Float16 h; } x; x.u = u; return (float)x.h;
}
__device__ __forceinline__ void async_cp16(const void* g, void* l) {
    __builtin_amdgcn_global_load_lds((const __attribute__((address_space(1))) unsigned*)g,
                                     (__attribute__((address_space(3))) unsigned*)l, 16, 0, 0);
}

__device__ __forceinline__ float wave_reduce_sum(float v) {
    #pragma unroll
    for (int off = 32; off; off >>= 1) v += __shfl_xor(v, off, 64);
    return v;
}
__device__ __forceinline__ float wave_reduce_max(float v) {
    #pragma unroll
    for (int off = 32; off; off >>= 1) v = fmaxf(v, __shfl_xor(v, off, 64));
    return v;
}

// ---------------- per-(b,c) stats: mean + rsqrt(var_unbiased + eps) ----------------
__global__ __launch_bounds__(256) void stats_kernel(const float* __restrict__ fc,
                                                    const float* __restrict__ fs,
                                                    float* __restrict__ stats) {
    const int idx = blockIdx.x;                    // 0..4095 (2048 fc + 2048 fs)
    const float* src = (idx < 2048 ? fc : fs) + (size_t)(idx & 2047) * N_SP;
    const int t = threadIdx.x;
    float s = 0.f, ss = 0.f;
    #pragma unroll
    for (int i = 0; i < 4; ++i) {
        float4 v = *(const float4*)(src + i * 1024 + t * 4);
        s  += v.x + v.y + v.z + v.w;
        ss += v.x * v.x + v.y * v.y + v.z * v.z + v.w * v.w;
    }
    s = wave_reduce_sum(s); ss = wave_reduce_sum(ss);
    __shared__ float rs[4], rss[4];
    const int wave = t >> 6;
    if ((t & 63) == 0) { rs[wave] = s; rss[wave] = ss; }
    __syncthreads();
    if (t == 0) {
        const float S  = rs[0] + rs[1] + rs[2] + rs[3];
        const float SS = rss[0] + rss[1] + rss[2] + rss[3];
        const float mean = S * (1.f / N_SP);
        const float var  = (SS - S * mean) * (1.f / (N_SP - 1));
        stats[idx * 2 + 0] = mean;
        stats[idx * 2 + 1] = rsqrtf(var + 1e-5f);
    }
}

// ---------------- normalize + transpose to fp16: x[b][c][n] f32 -> x̂ᵀ[b][n][c] f16 ----------------
__global__ __launch_bounds__(256) void norm_transpose(
        const float* __restrict__ fc, const float* __restrict__ fs,
        const float* __restrict__ stats,
        u16* __restrict__ xc, u16* __restrict__ xs) {
    __shared__ float tile[64][65];
    __shared__ float mi[64][2];
    const int t = threadIdx.x;
    const int n0 = blockIdx.x * 64, c0 = blockIdx.y * 64;
    const int z = blockIdx.z;                      // (which<<2)|b
    const int b = z & 3, which = z >> 2;
    const float* src = which ? fs : fc;
    u16* dst = which ? xs : xc;
    const float* st = stats + ((size_t)which * 2048 + b * 512 + c0) * 2;
    if (t < 128) ((float*)mi)[t] = st[t];
    __syncthreads();
    const int r = t >> 4, q4 = (t & 15) * 4;
    #pragma unroll
    for (int it = 0; it < 4; ++it) {
        const int row = it * 16 + r;
        float4 v = *(const float4*)(src + ((size_t)b * C_CH + c0 + row) * N_SP + n0 + q4);
        const float mean = mi[row][0], inv = mi[row][1];
        tile[row][q4 + 0] = (v.x - mean) * inv;
        tile[row][q4 + 1] = (v.y - mean) * inv;
        tile[row][q4 + 2] = (v.z - mean) * inv;
        tile[row][q4 + 3] = (v.w - mean) * inv;
    }
    __syncthreads();
    #pragma unroll
    for (int it = 0; it < 4; ++it) {
        const int nrow = it * 16 + r;
        ushort4 h4;
        h4.x = f2h(tile[q4 + 0][nrow]);
        h4.y = f2h(tile[q4 + 1][nrow]);
        h4.z = f2h(tile[q4 + 2][nrow]);
        h4.w = f2h(tile[q4 + 3][nrow]);
        *(ushort4*)(dst + ((size_t)b * N_SP + n0 + nrow) * C_CH + c0 + q4) = h4;
    }
}

// ---------------- weights fp32 -> fp16 (4 weights in one launch) ----------------
__global__ __launch_bounds__(256) void wconv(const float* __restrict__ W0, const float* __restrict__ W1,
                                             const float* __restrict__ W2, const float* __restrict__ W3,
                                             u16* __restrict__ dst) {
    const int i = blockIdx.x * 256 + threadIdx.x;         // 0 .. 4*262144-1
    const int w = i >> 18, r = i & 262143;
    const float* W = (w == 0) ? W0 : (w == 1) ? W1 : (w == 2) ? W2 : W3;
    dst[i] = f2h(W[r]);
}

// ---------------- fp16 MFMA GEMM (bt form): D[m][n] = sum_k A[m][k] * B[n][k] ----------------
enum { OUT_F32 = 0, OUT_F16 = 1 };

template<int OUTMODE, bool TABA, bool TABD>
__global__ __launch_bounds__(256) void gemm_bt(
    const u16* __restrict__ A, const u16* __restrict__ B, PtrTab tab,
    float* __restrict__ Df, u16* __restrict__ Dh,
    const float* __restrict__ bias_m, const float* __restrict__ bias_n,
    const float* __restrict__ res,
    int M, int N, int K, int lda, int ldb, int ldd,
    size_t sA, size_t sB, size_t sD, size_t sR)
{
    constexpr int TM = 128, TN = 128, BK = 32;
    __shared__ u16 smem[(TM + TN) * BK];
    u16* As = smem;
    u16* Bs = smem + TM * BK;

    const int t = threadIdx.x;
    const int l = t & 63, w = t >> 6;
    const int m0 = blockIdx.y * TM, n0 = blockIdx.x * TN;
    const size_t zb = blockIdx.z;
    const u16* pA = (TABA ? tab.p[zb] : A + zb * sA) + (size_t)m0 * lda;
    const u16* pB = B + zb * sB + (size_t)n0 * ldb;

    const int wr = (w & 1) * 64, wc = (w >> 1) * 64;

    f32x4 acc[4][4] = {};

    for (int k0 = 0; k0 < K; k0 += BK) {
        #pragma unroll
        for (int it = 0; it < 2; ++it) {
            const int L = it * 256 + t;
            const int row = L >> 2, cb = (L & 3) * 8;
            async_cp16(pA + (size_t)row * lda + k0 + cb, As + L * 8);
        }
        #pragma unroll
        for (int it = 0; it < 2; ++it) {
            const int L = it * 256 + t;
            const int row = L >> 2, cb = (L & 3) * 8;
            async_cp16(pB + (size_t)row * ldb + k0 + cb, Bs + L * 8);
        }
        __syncthreads();
        f16x8 af[4], bf[4];
        #pragma unroll
        for (int i = 0; i < 4; ++i)
            af[i] = *(const f16x8*)(As + (wr + i * 16 + (l & 15)) * BK + (l >> 4) * 8);
        #pragma unroll
        for (int j = 0; j < 4; ++j)
            bf[j] = *(const f16x8*)(Bs + (wc + j * 16 + (l & 15)) * BK + (l >> 4) * 8);
        #pragma unroll
        for (int i = 0; i < 4; ++i)
            #pragma unroll
            for (int j = 0; j < 4; ++j)
                acc[i][j] = __builtin_amdgcn_mfma_f32_16x16x32_f16(af[i], bf[j], acc[i][j], 0, 0, 0);
        __syncthreads();
    }

    const int em = m0 + wr + (l >> 4) * 4;
    const int en = n0 + wc + (l & 15);
    u16* pDh = nullptr; float* pDf = nullptr;
    if (OUTMODE == OUT_F16) pDh = (TABD ? tab.p[zb] : Dh + zb * sD);
    else                    pDf = Df + zb * sD;
    #pragma unroll
    for (int i = 0; i < 4; ++i) {
        #pragma unroll
        for (int j = 0; j < 4; ++j) {
            const int nn = en + j * 16;
            const float bn = bias_n ? bias_n[nn] : 0.f;
            #pragma unroll
            for (int r = 0; r < 4; ++r) {
                const int mm = em + i * 16 + r;
                float v = acc[i][j][r] + bn;
                if (bias_m) v += bias_m[mm];
                const size_t off = (size_t)mm * ldd + nn;
                if (OUTMODE == OUT_F32) {
                    if (res) v += res[zb * sR + off];
                    pDf[off] = v;
                } else {
                    pDh[off] = f2h(v);
                }
            }
        }
    }
}

// ---------------- softmax row-wise, fp16 in-place ----------------
__global__ __launch_bounds__(256) void softmax_kernel(PtrTab tab) {
    u16* row = tab.p[blockIdx.y] + (size_t)blockIdx.x * N_SP;
    const int t = threadIdx.x;
    u16 raw[16];
    *(uint4*)(raw + 0) = *(const uint4*)(row + t * 16);
    *(uint4*)(raw + 8) = *(const uint4*)(row + t * 16 + 8);
    float v[16];
    float mx = -1e30f;
    #pragma unroll
    for (int i = 0; i < 16; ++i) { v[i] = h2f(raw[i]); mx = fmaxf(mx, v[i]); }
    mx = wave_reduce_max(mx);
    __shared__ float red[4];
    const int wave = t >> 6;
    if ((t & 63) == 0) red[wave] = mx;
    __syncthreads();
    mx = fmaxf(fmaxf(red[0], red[1]), fmaxf(red[2], red[3]));
    float sum = 0.f;
    #pragma unroll
    for (int i = 0; i < 16; ++i) { v[i] = __expf(v[i] - mx); sum += v[i]; }
    sum = wave_reduce_sum(sum);
    __syncthreads();
    if ((t & 63) == 0) red[wave] = sum;
    __syncthreads();
    const float inv = 1.f / (red[0] + red[1] + red[2] + red[3]);
    #pragma unroll
    for (int i = 0; i < 16; ++i) raw[i] = f2h(v[i] * inv);
    *(uint4*)(row + t * 16)     = *(const uint4*)(raw + 0);
    *(uint4*)(row + t * 16 + 8) = *(const uint4*)(raw + 8);
}

extern "C" void kernel_launch(void* const* d_in, const int* in_sizes, int n_in,
                              void* d_out, int out_size, void* d_ws, size_t ws_size,
                              hipStream_t stream) {
    const float* f_c   = (const float*)d_in[0];
    const float* f_s   = (const float*)d_in[1];
    const float* W_c1  = (const float*)d_in[2];
    const float* b_c1  = (const float*)d_in[3];
    const float* W_s1  = (const float*)d_in[4];
    const float* b_s1  = (const float*)d_in[5];
    const float* W_s2  = (const float*)d_in[6];
    const float* b_s2  = (const float*)d_in[7];
    const float* W_csc = (const float*)d_in[8];
    const float* b_csc = (const float*)d_in[9];

    const size_t PB = (size_t)N_SP * C_CH;   // 2M elements per batch plane
    const size_t M1 = 1024 * 1024;

    // workspace layout in u16 units (total ≈ 178 MB):
    u16* ws  = (u16*)d_ws;
    u16* xc  = ws;                 // 8M  (dead after f conv)    [S0 aliases xc+xs]
    u16* xs  = ws + 8  * M1;       // 8M  (dead after h conv)
    u16* f_  = ws + 16 * M1;       // 8M  (dead after scores)    [O aliases f]
    u16* g_  = ws + 24 * M1;       // 8M  (dead after scores)
    u16* h_  = ws + 32 * M1;       // 8M
    u16* S1  = ws + 40 * M1;       // 16M
    u16* S2  = ws + 56 * M1;       // 16M
    u16* S3  = ws + 72 * M1;       // 16M
    u16* Wq  = ws + 88 * M1;       // 4 x 256K fp16 weights
    float* stats = (float*)(ws + 89 * M1);
    u16* O_  = f_;                 // alias
    u16* Wc1 = Wq, *Ws1 = Wq + 262144, *Ws2 = Wq + 524288, *Wcs = Wq + 786432;

    PtrTab Stab; Stab.p[0] = xc; Stab.p[1] = S1; Stab.p[2] = S2; Stab.p[3] = S3;
    PtrTab tab0 = Stab;  // dummy for non-TAB instantiations

    stats_kernel<<<4096, 256, 0, stream>>>(f_c, f_s, stats);
    norm_transpose<<<dim3(64, 8, 8), 256, 0, stream>>>(f_c, f_s, stats, xc, xs);
    wconv<<<4096, 256, 0, stream>>>(W_c1, W_s1, W_s2, W_csc, Wq);

    // fᵀ[i][o] = Σ_c x̂cᵀ[i][c] W_c1[o][c] + b_c1[o]
    gemm_bt<OUT_F16, false, false><<<dim3(4, 32, B_SZ), 256, 0, stream>>>(
        xc, Wc1, tab0, nullptr, f_, nullptr, b_c1, nullptr,
        N_SP, C_CH, C_CH, C_CH, C_CH, C_CH, PB, 0, PB, 0);
    // gᵀ[j][o]
    gemm_bt<OUT_F16, false, false><<<dim3(4, 32, B_SZ), 256, 0, stream>>>(
        xs, Ws1, tab0, nullptr, g_, nullptr, b_s1, nullptr,
        N_SP, C_CH, C_CH, C_CH, C_CH, C_CH, PB, 0, PB, 0);
    // h[c][j] = Σ_k W_s2[c][k] x̂sᵀ[j][k] + b_s2[c]
    gemm_bt<OUT_F16, false, false><<<dim3(32, 4, B_SZ), 256, 0, stream>>>(
        Ws2, xs, tab0, nullptr, h_, b_s2, nullptr, nullptr,
        C_CH, N_SP, C_CH, C_CH, C_CH, N_SP, 0, PB, PB, 0);

    // S_b[i][j] = Σ_c fᵀ[i][c] gᵀ[j][c]   (fp16 out, per-batch buffer via table)
    gemm_bt<OUT_F16, false, true><<<dim3(32, 32, B_SZ), 256, 0, stream>>>(
        f_, g_, Stab, nullptr, nullptr, nullptr, nullptr, nullptr,
        N_SP, N_SP, C_CH, C_CH, C_CH, N_SP, PB, PB, 0, 0);

    softmax_kernel<<<dim3(N_SP, B_SZ), 256, 0, stream>>>(Stab);

    // Oᵀ[i][c] = Σ_j P_b[i][j] h[c][j]
    gemm_bt<OUT_F16, true, false><<<dim3(4, 32, B_SZ), 256, 0, stream>>>(
        nullptr, h_, Stab, nullptr, O_, nullptr, nullptr, nullptr,
        N_SP, C_CH, N_SP, N_SP, N_SP, C_CH, 0, PB, PB, 0);

    // out[o][i] = Σ_c W_csc[o][c] Oᵀ[i][c] + b_csc[o] + f_c
    gemm_bt<OUT_F32, false, false><<<dim3(32, 4, B_SZ), 256, 0, stream>>>(
        Wcs, O_, tab0, (float*)d_out, nullptr, b_csc, nullptr, f_c,
        C_CH, N_SP, C_CH, C_CH, C_CH, N_SP, 0, PB, PB, PB);
}